// Round 11
// baseline (499.462 us; speedup 1.0000x reference)
//
#include <hip/hip_runtime.h>
#include <math.h>

// N=50000 nodes, E=800000 edges, F_IN=33, H=128, G=64 graphs.
static constexpr int F_IN = 33;
static constexpr int H    = 128;
static constexpr int GG   = 64;

typedef __attribute__((ext_vector_type(8))) short short8;
typedef __attribute__((ext_vector_type(4))) float f32x4;

__device__ __forceinline__ unsigned short f2bf(float f) {
  union { float f; unsigned u; } v; v.f = f;
  unsigned r = v.u + 0x7fffu + ((v.u >> 16) & 1u);   // RNE
  return (unsigned short)(r >> 16);
}
__device__ __forceinline__ float bf2f(unsigned short b) {
  union { unsigned u; float f; } v; v.u = ((unsigned)b) << 16;
  return v.f;
}

// Async global->LDS copy, 16B per lane, wave-uniform LDS base (lane-linear).
using gas_u32 = const __attribute__((address_space(1))) unsigned int*;
using las_u32 = __attribute__((address_space(3))) unsigned int*;
__device__ __forceinline__ void ld_lds16(const unsigned short* g, unsigned short* l) {
  __builtin_amdgcn_global_load_lds((gas_u32)(const void*)g, (las_u32)(void*)l, 16, 0, 0);
}

// ---------------- prep: csr hist + W conv + x conv, one launch --------------

struct PrepArgs {
  const int* dst; int* M; int E; int NB; int NBLK;
  const float* w[6]; unsigned short* o[6]; int K[6]; int Kp[6];
  const float* x; unsigned short* x64; int N;
};

__global__ void prep(PrepArgs a) {
  const int b = blockIdx.x, tx = threadIdx.x;
  if (b < a.NBLK) {
    __shared__ int hist[256];
    for (int i = tx; i < a.NB; i += 256) hist[i] = 0;
    __syncthreads();
    const int chunk = (a.E + a.NBLK - 1) / a.NBLK;
    const int lo = b * chunk;
    const int hi = min(lo + chunk, a.E);
    for (int i = lo + tx; i < hi; i += 256)
      atomicAdd(&hist[a.dst[i] >> 8], 1);
    __syncthreads();
    for (int bb = tx; bb < a.NB; bb += 256)
      a.M[bb * a.NBLK + b] = hist[bb];
  } else if (b < a.NBLK + 384) {
    const int wb = b - a.NBLK;
    const int wi = wb >> 6;
    const int Kp = a.Kp[wi];
    const int i = (wb & 63) * 256 + tx;
    if (i < H * Kp) {
      const int nn = i / Kp, k = i - nn * Kp;
      float v = (k < a.K[wi]) ? a.w[wi][(size_t)k * H + nn] : 0.f;
      a.o[wi][(size_t)nn * Kp + (((k >> 3) ^ (nn & 7)) << 3) + (k & 7)] = f2bf(v);
    }
  } else {
    const int xb = b - a.NBLK - 384;
    for (int r = 0; r < 4; ++r) {
      const int idx = xb * 1024 + r * 256 + tx;
      const int node = idx >> 6, f = idx & 63;
      if (node < a.N) {
        float v = (f < F_IN) ? a.x[(size_t)node * F_IN + f] : 0.f;
        a.x64[(size_t)node * 64 + (((f >> 3) ^ (node & 7)) << 3) + (f & 7)] = f2bf(v);
      }
    }
  }
}

// ---------------- CSR: per-bucket scan of M + bucket totals -----------------

__global__ void scanA(int* __restrict__ M, int* __restrict__ bucketTotal, int NBLK) {
  __shared__ int scn[256];
  const int b = blockIdx.x, t = threadIdx.x;
  int v = M[b * NBLK + t];
  scn[t] = v;
  __syncthreads();
  for (int off = 1; off < 256; off <<= 1) {
    int add = (t >= off) ? scn[t - off] : 0;
    __syncthreads();
    scn[t] += add;
    __syncthreads();
  }
  M[b * NBLK + t] = scn[t] - v;
  if (t == 255) bucketTotal[b] = scn[255];
}

__global__ void csr_p2(const int* __restrict__ src, const int* __restrict__ dst,
                       const int* __restrict__ M, const int* __restrict__ bucketTotal,
                       unsigned* __restrict__ tmp, int E, int NB) {
  __shared__ int scn[256];
  __shared__ int cur[256];
  const int tx = threadIdx.x, blk = blockIdx.x, nblk = gridDim.x;
  int v = (tx < NB) ? bucketTotal[tx] : 0;
  scn[tx] = v;
  __syncthreads();
  for (int off = 1; off < 256; off <<= 1) {
    int add = (tx >= off) ? scn[tx - off] : 0;
    __syncthreads();
    scn[tx] += add;
    __syncthreads();
  }
  int e = scn[tx] - v;
  __syncthreads();
  scn[tx] = e;
  __syncthreads();
  for (int b = tx; b < NB; b += 256) cur[b] = M[b * nblk + blk] + scn[b];
  __syncthreads();
  const int chunk = (E + nblk - 1) / nblk;
  const int lo = blk * chunk;
  const int hi = min(lo + chunk, E);
  for (int i = lo + tx; i < hi; i += 256) {
    int d = dst[i];
    int pos = atomicAdd(&cur[d >> 8], 1);
    tmp[pos] = ((unsigned)src[i] << 8) | (unsigned)(d & 255);   // src < 2^24
  }
}

__global__ void csr_p3(const unsigned* __restrict__ tmp, const int* __restrict__ bucketTotal,
                       int* __restrict__ rowptr, int* __restrict__ srcList,
                       int n, int E, int NB) {
  __shared__ int scn[256];
  __shared__ int hist[256];
  __shared__ int s2[256];
  const int b = blockIdx.x, tx = threadIdx.x;
  int v = (tx < NB) ? bucketTotal[tx] : 0;
  scn[tx] = v;
  __syncthreads();
  for (int off = 1; off < 256; off <<= 1) {
    int add = (tx >= off) ? scn[tx - off] : 0;
    __syncthreads();
    scn[tx] += add;
    __syncthreads();
  }
  int e = scn[tx] - v;
  __syncthreads();
  scn[tx] = e;
  __syncthreads();
  const int segStart = scn[b];
  const int segEnd = (b + 1 < NB) ? scn[b + 1] : E;
  if (b == 0 && tx == 0) rowptr[n] = E;
  const int nodeBase = b << 8;
  hist[tx] = 0;
  __syncthreads();
  for (int i = segStart + tx; i < segEnd; i += 256)
    atomicAdd(&hist[tmp[i] & 255u], 1);
  __syncthreads();
  int hv = hist[tx];
  s2[tx] = hv;
  __syncthreads();
  for (int off = 1; off < 256; off <<= 1) {
    int add = (tx >= off) ? s2[tx - off] : 0;
    __syncthreads();
    s2[tx] += add;
    __syncthreads();
  }
  int ex = s2[tx] - hv;                    // exclusive prefix within bucket
  if (nodeBase + tx < n) rowptr[nodeBase + tx] = segStart + ex;
  hist[tx] = ex;                           // reuse as cursor
  __syncthreads();
  for (int i = segStart + tx; i < segEnd; i += 256) {
    unsigned ee = tmp[i];
    int pos = atomicAdd(&hist[ee & 255u], 1);
    srcList[segStart + pos] = (int)(ee >> 8);
  }
}

// ------ Fused gather + GIN MLP: A = h + sum(neigh); C = mlp(A); + pool ------
// Persistent blocks (grid=256, 1 block/CU). Each block gathers its 64-row
// tile DIRECTLY into LDS (no global A round-trip): wave wv gathers rows
// wv*8..wv*8+7; per row, CH lanes cover the row's uint4 chunks and 64/CH
// edge-groups pull edges concurrently; reduce via shfl, ds_write to Als.
// Gather for tile t+step is issued after GEMM2 of tile t (before the
// barrier) so its latency overlaps compute. Z in LDS; pool in LDS ->
// per-block slab slice; W staged once via global_load_lds.

template <int K1, bool STORE>
__global__ __launch_bounds__(512, 1) void gin_fused(
    const unsigned short* __restrict__ Hin,  // source rows: K1 ushorts, swizzled
    const int* __restrict__ rowptr, const int* __restrict__ srcList,
    const unsigned short* __restrict__ W1t,  // 128 x K1 bf16 (swizzled)
    const unsigned short* __restrict__ W2t,  // 128 x 128 bf16 (swizzled)
    const float* __restrict__ b1, const float* __restrict__ gam,
    const float* __restrict__ bet, const float* __restrict__ mu,
    const float* __restrict__ var, const float* __restrict__ b2,
    unsigned short* __restrict__ Pout,       // n x 128 bf16 (swizzled) or null
    const int* __restrict__ batch,
    float* __restrict__ slab,                // 256 x 8192 per-block partials
    int n) {
  constexpr int CH = K1 / 8;                 // uint4 chunks per row (8 or 16)
  constexpr int EG = 64 / CH;                // edges per vmem instr (8 or 4)
  constexpr int NLD = 16 / EG;               // loads per 16-edge burst (2 or 4)
  __shared__ __align__(16) unsigned short W1ls[128 * K1];
  __shared__ __align__(16) unsigned short W2ls[128 * 128];
  __shared__ __align__(16) unsigned short Als[64 * K1];
  __shared__ __align__(16) unsigned short Zls[64 * 128];
  __shared__ __align__(16) float poolLs[GG * H];   // 32 KB
  __shared__ float sc1[128], sh1[128], b2l[128];

  const int tx = threadIdx.x;
  const int wv = tx >> 6;                 // wave 0..7
  const int lane = tx & 63;
  const int q = lane >> 4, m = lane & 15;
  const int rowGroup = (wv >> 1) * 16;
  const int colHalf = (wv & 1) * 64;
  const int ntiles = (n + 63) >> 6;
  const int step = gridDim.x;
  const int grp = lane / CH;              // edge group
  const int lc = lane & (CH - 1);         // logical chunk within row
  const uint4* Hrow = (const uint4*)Hin;
  uint4* Als4 = (uint4*)Als;

  // Stage W once (async; each wave copies distinct 1024B segments).
  constexpr int W1SEG = 128 * K1 / 512;
  for (int s = wv; s < W1SEG; s += 8)
    ld_lds16(W1t + s * 512 + lane * 8, &W1ls[s * 512]);
  for (int s = wv; s < 32; s += 8)
    ld_lds16(W2t + s * 512 + lane * 8, &W2ls[s * 512]);

  {
    f32x4* pl = (f32x4*)poolLs;
    for (int i = tx; i < GG * H / 4; i += 512) pl[i] = (f32x4)(0.f);
  }
  if (tx < 128) {                          // fold bias1 into BN affine
    float s = gam[tx] * rsqrtf(var[tx] + 1e-5f);
    sc1[tx] = s;
    sh1[tx] = bet[tx] + (b1[tx] - mu[tx]) * s;
  } else if (tx < 256) {
    b2l[tx - 128] = b2[tx - 128];
  }

  // Gather one tile's 64 rows into Als (this wave's 8 rows).
  auto gather = [&](int t) {
    const int rbase = t * 64 + wv * 8;
#pragma unroll 2
    for (int i = 0; i < 8; ++i) {
      const int r = rbase + i;             // wave-uniform
      if (r >= n) break;
      const int beg = rowptr[r], end = rowptr[r + 1];
      float a0 = 0, a1 = 0, a2 = 0, a3 = 0, a4 = 0, a5 = 0, a6 = 0, a7 = 0;
      auto addv = [&](uint4 vv) {
        a0 += bf2f((unsigned short)vv.x); a1 += bf2f((unsigned short)(vv.x >> 16));
        a2 += bf2f((unsigned short)vv.y); a3 += bf2f((unsigned short)(vv.y >> 16));
        a4 += bf2f((unsigned short)vv.z); a5 += bf2f((unsigned short)(vv.z >> 16));
        a6 += bf2f((unsigned short)vv.w); a7 += bf2f((unsigned short)(vv.w >> 16));
      };
      int j = beg;
      for (; j + 16 <= end; j += 16) {     // 16-edge burst, NLD loads in flight
        int s[NLD]; uint4 v[NLD];
#pragma unroll
        for (int k = 0; k < NLD; ++k) s[k] = srcList[j + EG * k + grp];
#pragma unroll
        for (int k = 0; k < NLD; ++k) v[k] = Hrow[(size_t)s[k] * CH + (lc ^ (s[k] & 7))];
#pragma unroll
        for (int k = 0; k < NLD; ++k) addv(v[k]);
      }
      for (; j < end; j += EG) {           // EG-edge tail
        const int idx = j + grp;
        int s0 = srcList[min(idx, end - 1)];
        if (idx < end) addv(Hrow[(size_t)s0 * CH + (lc ^ (s0 & 7))]);
      }
#pragma unroll
      for (int d = 32; d >= CH; d >>= 1) { // reduce edge-groups -> lanes<CH
        a0 += __shfl_down(a0, d); a1 += __shfl_down(a1, d);
        a2 += __shfl_down(a2, d); a3 += __shfl_down(a3, d);
        a4 += __shfl_down(a4, d); a5 += __shfl_down(a5, d);
        a6 += __shfl_down(a6, d); a7 += __shfl_down(a7, d);
      }
      if (lane < CH) {
        addv(Hrow[(size_t)r * CH + (lc ^ (r & 7))]);   // self term
        uint4 o;
        o.x = ((unsigned)f2bf(a1) << 16) | (unsigned)f2bf(a0);
        o.y = ((unsigned)f2bf(a3) << 16) | (unsigned)f2bf(a2);
        o.z = ((unsigned)f2bf(a5) << 16) | (unsigned)f2bf(a4);
        o.w = ((unsigned)f2bf(a7) << 16) | (unsigned)f2bf(a6);
        Als4[(wv * 8 + i) * CH + (lc ^ i)] = o;        // local row&7 == i
      }
    }
  };

  int tile = blockIdx.x;
  if (tile < ntiles) gather(tile);
  __syncthreads();                         // drains W + Als(tile)

  while (tile < ntiles) {
    // ---- GEMM1: Z = relu(BN(A @ W1 + b1)) ----
    f32x4 acc[4];
#pragma unroll
    for (int t4 = 0; t4 < 4; ++t4) acc[t4] = (f32x4)(0.f);
    const int am = rowGroup + m;
#pragma unroll
    for (int kc = 0; kc < K1 / 32; ++kc) {
      short8 af = *(const short8*)&Als[am * K1 + (((kc * 4 + q) ^ (am & 7)) << 3)];
#pragma unroll
      for (int t4 = 0; t4 < 4; ++t4) {
        const int bn = colHalf + t4 * 16 + m;
        short8 bf = *(const short8*)&W1ls[bn * K1 + (((kc * 4 + q) ^ (bn & 7)) << 3)];
        acc[t4] = __builtin_amdgcn_mfma_f32_16x16x32_bf16(af, bf, acc[t4], 0, 0, 0);
      }
    }
#pragma unroll
    for (int t4 = 0; t4 < 4; ++t4) {       // epilogue -> Zls (bf16, swizzled)
      const int col = colHalf + t4 * 16 + m;
      const float s = sc1[col], hh = sh1[col];
#pragma unroll
      for (int reg = 0; reg < 4; ++reg) {
        const int r = rowGroup + q * 4 + reg;
        float z = fmaf(acc[t4][reg], s, hh);
        z = z > 0.f ? z : 0.f;
        Zls[r * 128 + (((col >> 3) ^ (r & 7)) << 3) + (col & 7)] = f2bf(z);
      }
    }
    __syncthreads();                       // Zls ready; Als readers done
    // ---- GEMM2: C = relu(Z @ W2 + b2) ----
#pragma unroll
    for (int t4 = 0; t4 < 4; ++t4) acc[t4] = (f32x4)(0.f);
#pragma unroll
    for (int kc = 0; kc < 4; ++kc) {
      short8 af = *(const short8*)&Zls[am * 128 + (((kc * 4 + q) ^ (am & 7)) << 3)];
#pragma unroll
      for (int t4 = 0; t4 < 4; ++t4) {
        const int bn = colHalf + t4 * 16 + m;
        short8 bf = *(const short8*)&W2ls[bn * 128 + (((kc * 4 + q) ^ (bn & 7)) << 3)];
        acc[t4] = __builtin_amdgcn_mfma_f32_16x16x32_bf16(af, bf, acc[t4], 0, 0, 0);
      }
    }
    const int r0 = tile * 64 + rowGroup + q * 4;
    int gb4[4];
#pragma unroll
    for (int reg = 0; reg < 4; ++reg) gb4[reg] = (r0 + reg < n) ? batch[r0 + reg] : -1;
#pragma unroll
    for (int t4 = 0; t4 < 4; ++t4) {
      const int col = colHalf + t4 * 16 + m;
      float v[4];
#pragma unroll
      for (int reg = 0; reg < 4; ++reg) {
        float z = acc[t4][reg] + b2l[col];
        v[reg] = z > 0.f ? z : 0.f;
      }
      if constexpr (STORE) {
#pragma unroll
        for (int reg = 0; reg < 4; ++reg) {
          const int row = r0 + reg;
          if (row < n)
            Pout[(size_t)row * 128 + (((col >> 3) ^ (row & 7)) << 3) + (col & 7)] = f2bf(v[reg]);
        }
      }
      int gcur = -1; float ps = 0.f;       // batch sorted -> run-length flush
#pragma unroll
      for (int reg = 0; reg < 4; ++reg) {
        if (gb4[reg] < 0) break;
        if (gb4[reg] != gcur) {
          if (gcur >= 0) atomicAdd(&poolLs[gcur * H + col], ps);
          gcur = gb4[reg]; ps = v[reg];
        } else {
          ps += v[reg];
        }
      }
      if (gcur >= 0) atomicAdd(&poolLs[gcur * H + col], ps);
    }
    const int nt = tile + step;
    if (nt < ntiles) gather(nt);           // overlaps other waves' GEMM2
    __syncthreads();                       // Als(nt) ready; Zls free
    tile = nt;
  }

  // Flush per-block pool partial to private slab slice (no contention).
  __syncthreads();
  {
    const f32x4* pl = (const f32x4*)poolLs;
    f32x4* sl = (f32x4*)(slab + (size_t)blockIdx.x * (GG * H));
    for (int i = tx; i < GG * H / 4; i += 512) sl[i] = pl[i];
  }
}

// ------- Head: slab reduce (256 slices x 3 layers) + MLP + sigmoid ----------

__global__ void head2(const float* __restrict__ slab,
                      const float* __restrict__ l1w, const float* __restrict__ l1b,
                      const float* __restrict__ l2w, const float* __restrict__ l2b,
                      const float* __restrict__ l3w, const float* __restrict__ l3b,
                      float* __restrict__ out) {
  const int g = blockIdx.x;
  const int t = threadIdx.x;  // 256 threads
  __shared__ float hin[3 * H];
  __shared__ float t1[50];
  __shared__ float t2[20];
  for (int idx = t; idx < 3 * H; idx += 256) {
    const int l = idx >> 7, f = idx & 127;
    const float* s = slab + (size_t)l * 256 * (GG * H) + (size_t)g * H + f;
    float acc = 0.f;
#pragma unroll 8
    for (int b = 0; b < 256; ++b) acc += s[(size_t)b * (GG * H)];
    hin[idx] = acc;
  }
  __syncthreads();
  if (t < 50) {
    float s = l1b[t];
    for (int k = 0; k < 3 * H; ++k) s = fmaf(hin[k], l1w[k * 50 + t], s);
    t1[t] = s > 0.f ? s : 0.f;
  }
  __syncthreads();
  if (t < 20) {
    float s = l2b[t];
    for (int k = 0; k < 50; ++k) s = fmaf(t1[k], l2w[k * 20 + t], s);
    t2[t] = s > 0.f ? s : 0.f;
  }
  __syncthreads();
  if (t == 0) {
    float s = l3b[0];
    for (int k = 0; k < 20; ++k) s = fmaf(t2[k], l3w[k], s);
    out[g] = 1.f / (1.f + expf(-s));
  }
}

// ---------------- launch ----------------------------------------------------

extern "C" void kernel_launch(void* const* d_in, const int* in_sizes, int n_in,
                              void* d_out, int out_size, void* d_ws, size_t ws_size,
                              hipStream_t stream) {
  const float* x    = (const float*)d_in[0];
  const int* ei     = (const int*)d_in[1];
  const int* batch  = (const int*)d_in[2];
  const int N = in_sizes[2];
  const int E = in_sizes[1] / 2;
  const int* src = ei;
  const int* dst = ei + E;

  const float* w1[3]; const float* b1[3]; const float* gm[3]; const float* be[3];
  const float* mu[3]; const float* vr[3]; const float* w2[3]; const float* b2[3];
  for (int l = 0; l < 3; ++l) {
    int b = 3 + 8 * l;
    w1[l] = (const float*)d_in[b + 0];
    b1[l] = (const float*)d_in[b + 1];
    gm[l] = (const float*)d_in[b + 2];
    be[l] = (const float*)d_in[b + 3];
    mu[l] = (const float*)d_in[b + 4];
    vr[l] = (const float*)d_in[b + 5];
    w2[l] = (const float*)d_in[b + 6];
    b2[l] = (const float*)d_in[b + 7];
  }
  const float* l1w = (const float*)d_in[27];
  const float* l1b = (const float*)d_in[28];
  const float* l2w = (const float*)d_in[29];
  const float* l2b = (const float*)d_in[30];
  const float* l3w = (const float*)d_in[31];
  const float* l3b = (const float*)d_in[32];

  // workspace carve-up
  char* ws = (char*)d_ws;
  size_t off = 0;
  auto take = [&](size_t bytes) {
    size_t p = off;
    off += (bytes + 255) & ~(size_t)255;
    return p;
  };
  unsigned short* P  = (unsigned short*)(ws + take((size_t)N * H * 2));   // layer out (bf16, swizzled)
  unsigned short* x64= (unsigned short*)(ws + take((size_t)N * 64 * 2));  // x as bf16 Nx64 swizzled
  float* slab   = (float*)(ws + take((size_t)3 * 256 * GG * H * 4));      // 24 MB partials
  int* rowptr   = (int*)(ws + take((size_t)(N + 1) * 4));
  int* M        = (int*)(ws + take((size_t)256 * 256 * 4));               // bucket counts/offsets
  int* srcList  = (int*)(ws + take((size_t)E * 4));
  unsigned* tmp = (unsigned*)(ws + take((size_t)E * 4));                  // packed (src<<8|dstLocal)
  int* bucketTotal = (int*)(ws + take((size_t)256 * 4));
  unsigned short* Wt[6];
  for (int i = 0; i < 6; ++i) Wt[i] = (unsigned short*)(ws + take((size_t)H * H * 2));
  (void)ws_size; (void)n_in; (void)out_size;

  const int NBLK = 256;
  const int NB = (N + 255) >> 8;          // buckets of 256 nodes (<= 256)
  const int XB = ((size_t)N * 64 + 1023) / 1024;

  // prep: csr hist + wconv + xconv, one launch
  PrepArgs pa;
  pa.dst = dst; pa.M = M; pa.E = E; pa.NB = NB; pa.NBLK = NBLK;
  pa.w[0] = w1[0]; pa.K[0] = F_IN; pa.Kp[0] = 64;
  pa.w[1] = w2[0]; pa.K[1] = H;    pa.Kp[1] = H;
  pa.w[2] = w1[1]; pa.K[2] = H;    pa.Kp[2] = H;
  pa.w[3] = w2[1]; pa.K[3] = H;    pa.Kp[3] = H;
  pa.w[4] = w1[2]; pa.K[4] = H;    pa.Kp[4] = H;
  pa.w[5] = w2[2]; pa.K[5] = H;    pa.Kp[5] = H;
  for (int i = 0; i < 6; ++i) pa.o[i] = Wt[i];
  pa.x = x; pa.x64 = x64; pa.N = N;
  prep<<<NBLK + 384 + XB, 256, 0, stream>>>(pa);

  // CSR: per-bucket scan, scatter to tmp, final sort into srcList + rowptr
  scanA<<<NB, 256, 0, stream>>>(M, bucketTotal, NBLK);
  csr_p2<<<NBLK, 256, 0, stream>>>(src, dst, M, bucketTotal, tmp, E, NB);
  csr_p3<<<NB, 256, 0, stream>>>(tmp, bucketTotal, rowptr, srcList, N, E, NB);

  // ---- layer 1 (fused gather from x64, K padded 33 -> 64) ----
  gin_fused<64, true><<<256, 512, 0, stream>>>(
      x64, rowptr, srcList, Wt[0], Wt[1],
      b1[0], gm[0], be[0], mu[0], vr[0], b2[0],
      P, batch, slab, N);

  // ---- layer 2 (fused gather from P) ----
  gin_fused<128, true><<<256, 512, 0, stream>>>(
      P, rowptr, srcList, Wt[2], Wt[3],
      b1[1], gm[1], be[1], mu[1], vr[1], b2[1],
      P, batch, slab + (size_t)256 * GG * H, N);

  // ---- layer 3 (fused gather from P; pooled only) ----
  gin_fused<128, false><<<256, 512, 0, stream>>>(
      P, rowptr, srcList, Wt[4], Wt[5],
      b1[2], gm[2], be[2], mu[2], vr[2], b2[2],
      nullptr, batch, slab + (size_t)2 * 256 * GG * H, N);

  // ---- head (slab reduce + MLP + sigmoid) ----
  head2<<<GG, 256, 0, stream>>>(slab, l1w, l1b, l2w, l2b, l3w, l3b, (float*)d_out);
}

// Round 12
// 337.100 us; speedup vs baseline: 1.4816x; 1.4816x over previous
//
#include <hip/hip_runtime.h>
#include <math.h>

// N=50000 nodes, E=800000 edges, F_IN=33, H=128, G=64 graphs.
static constexpr int F_IN = 33;
static constexpr int H    = 128;
static constexpr int GG   = 64;

typedef __attribute__((ext_vector_type(8))) short short8;
typedef __attribute__((ext_vector_type(4))) float f32x4;

__device__ __forceinline__ unsigned short f2bf(float f) {
  union { float f; unsigned u; } v; v.f = f;
  unsigned r = v.u + 0x7fffu + ((v.u >> 16) & 1u);   // RNE
  return (unsigned short)(r >> 16);
}
__device__ __forceinline__ float bf2f(unsigned short b) {
  union { unsigned u; float f; } v; v.u = ((unsigned)b) << 16;
  return v.f;
}

// Async global->LDS copy, 16B per lane, wave-uniform LDS base (lane-linear).
using gas_u32 = const __attribute__((address_space(1))) unsigned int*;
using las_u32 = __attribute__((address_space(3))) unsigned int*;
__device__ __forceinline__ void ld_lds16(const unsigned short* g, unsigned short* l) {
  __builtin_amdgcn_global_load_lds((gas_u32)(const void*)g, (las_u32)(void*)l, 16, 0, 0);
}

// ---------------- prep: csr hist + W conv + x conv, one launch --------------

struct PrepArgs {
  const int* dst; int* M; int E; int NB; int NBLK;
  const float* w[6]; unsigned short* o[6]; int K[6]; int Kp[6];
  const float* x; unsigned short* x64; int N;
};

__global__ void prep(PrepArgs a) {
  const int b = blockIdx.x, tx = threadIdx.x;
  if (b < a.NBLK) {
    __shared__ int hist[256];
    for (int i = tx; i < a.NB; i += 256) hist[i] = 0;
    __syncthreads();
    const int chunk = (a.E + a.NBLK - 1) / a.NBLK;
    const int lo = b * chunk;
    const int hi = min(lo + chunk, a.E);
    for (int i = lo + tx; i < hi; i += 256)
      atomicAdd(&hist[a.dst[i] >> 8], 1);
    __syncthreads();
    for (int bb = tx; bb < a.NB; bb += 256)
      a.M[bb * a.NBLK + b] = hist[bb];
  } else if (b < a.NBLK + 384) {
    const int wb = b - a.NBLK;
    const int wi = wb >> 6;
    const int Kp = a.Kp[wi];
    const int i = (wb & 63) * 256 + tx;
    if (i < H * Kp) {
      const int nn = i / Kp, k = i - nn * Kp;
      float v = (k < a.K[wi]) ? a.w[wi][(size_t)k * H + nn] : 0.f;
      a.o[wi][(size_t)nn * Kp + (((k >> 3) ^ (nn & 7)) << 3) + (k & 7)] = f2bf(v);
    }
  } else {
    const int xb = b - a.NBLK - 384;
    for (int r = 0; r < 4; ++r) {
      const int idx = xb * 1024 + r * 256 + tx;
      const int node = idx >> 6, f = idx & 63;
      if (node < a.N) {
        float v = (f < F_IN) ? a.x[(size_t)node * F_IN + f] : 0.f;
        a.x64[(size_t)node * 64 + (((f >> 3) ^ (node & 7)) << 3) + (f & 7)] = f2bf(v);
      }
    }
  }
}

// ---------------- CSR: per-bucket scan of M + bucket totals -----------------

__global__ void scanA(int* __restrict__ M, int* __restrict__ bucketTotal, int NBLK) {
  __shared__ int scn[256];
  const int b = blockIdx.x, t = threadIdx.x;
  int v = M[b * NBLK + t];
  scn[t] = v;
  __syncthreads();
  for (int off = 1; off < 256; off <<= 1) {
    int add = (t >= off) ? scn[t - off] : 0;
    __syncthreads();
    scn[t] += add;
    __syncthreads();
  }
  M[b * NBLK + t] = scn[t] - v;
  if (t == 255) bucketTotal[b] = scn[255];
}

__global__ void csr_p2(const int* __restrict__ src, const int* __restrict__ dst,
                       const int* __restrict__ M, const int* __restrict__ bucketTotal,
                       unsigned* __restrict__ tmp, int E, int NB) {
  __shared__ int scn[256];
  __shared__ int cur[256];
  const int tx = threadIdx.x, blk = blockIdx.x, nblk = gridDim.x;
  int v = (tx < NB) ? bucketTotal[tx] : 0;
  scn[tx] = v;
  __syncthreads();
  for (int off = 1; off < 256; off <<= 1) {
    int add = (tx >= off) ? scn[tx - off] : 0;
    __syncthreads();
    scn[tx] += add;
    __syncthreads();
  }
  int e = scn[tx] - v;                    // exclusive bucket offset
  __syncthreads();
  scn[tx] = e;
  __syncthreads();
  for (int b = tx; b < NB; b += 256) cur[b] = M[b * nblk + blk] + scn[b];
  __syncthreads();
  const int chunk = (E + nblk - 1) / nblk;
  const int lo = blk * chunk;
  const int hi = min(lo + chunk, E);
  for (int i = lo + tx; i < hi; i += 256) {
    int d = dst[i];
    int pos = atomicAdd(&cur[d >> 8], 1);
    tmp[pos] = ((unsigned)src[i] << 8) | (unsigned)(d & 255);   // src < 2^24
  }
}

__global__ void csr_p3(const unsigned* __restrict__ tmp, const int* __restrict__ bucketTotal,
                       int* __restrict__ rowptr, int* __restrict__ srcList,
                       int n, int E, int NB) {
  __shared__ int scn[256];
  __shared__ int hist[256];
  __shared__ int s2[256];
  const int b = blockIdx.x, tx = threadIdx.x;
  int v = (tx < NB) ? bucketTotal[tx] : 0;
  scn[tx] = v;
  __syncthreads();
  for (int off = 1; off < 256; off <<= 1) {
    int add = (tx >= off) ? scn[tx - off] : 0;
    __syncthreads();
    scn[tx] += add;
    __syncthreads();
  }
  int e = scn[tx] - v;
  __syncthreads();
  scn[tx] = e;
  __syncthreads();
  const int segStart = scn[b];
  const int segEnd = (b + 1 < NB) ? scn[b + 1] : E;
  if (b == 0 && tx == 0) rowptr[n] = E;
  const int nodeBase = b << 8;
  hist[tx] = 0;
  __syncthreads();
  for (int i = segStart + tx; i < segEnd; i += 256)
    atomicAdd(&hist[tmp[i] & 255u], 1);
  __syncthreads();
  int hv = hist[tx];
  s2[tx] = hv;
  __syncthreads();
  for (int off = 1; off < 256; off <<= 1) {
    int add = (tx >= off) ? s2[tx - off] : 0;
    __syncthreads();
    s2[tx] += add;
    __syncthreads();
  }
  int ex = s2[tx] - hv;                    // exclusive prefix within bucket
  if (nodeBase + tx < n) rowptr[nodeBase + tx] = segStart + ex;
  hist[tx] = ex;                           // reuse as cursor
  __syncthreads();
  for (int i = segStart + tx; i < segEnd; i += 256) {
    unsigned ee = tmp[i];
    int pos = atomicAdd(&hist[ee & 255u], 1);
    srcList[segStart + pos] = (int)(ee >> 8);
  }
}

// ---------------- Aggregation (gather), bf16, swizzled rows, uint4 ----------
// High-occupancy standalone gathers: latency x concurrency-bound -> need
// many waves/CU (round 11's low-TLP fusion regressed 1.5x; keep separate).

__global__ void gather_h(const unsigned short* __restrict__ h, const int* __restrict__ rowptr,
                         const int* __restrict__ srcList, unsigned short* __restrict__ out, int n) {
  const int tx = threadIdx.x;
  const int node = blockIdx.x * 4 + (tx >> 6);
  if (node >= n) return;
  const int lane = tx & 63;
  const int grp = lane >> 4;              // 4 edge-groups
  const int l16 = lane & 15;              // logical 16B chunk
  const uint4* h16 = (const uint4*)h;     // row = 16 uint4
  auto roff = [&](int r) { return (size_t)r * 16 + (l16 ^ (r & 7)); };

  const int beg = rowptr[node], end = rowptr[node + 1];
  float a0=0,a1=0,a2=0,a3=0,a4=0,a5=0,a6=0,a7=0;
  auto addv = [&](uint4 vv) {
    a0 += bf2f((unsigned short)vv.x); a1 += bf2f((unsigned short)(vv.x >> 16));
    a2 += bf2f((unsigned short)vv.y); a3 += bf2f((unsigned short)(vv.y >> 16));
    a4 += bf2f((unsigned short)vv.z); a5 += bf2f((unsigned short)(vv.z >> 16));
    a6 += bf2f((unsigned short)vv.w); a7 += bf2f((unsigned short)(vv.w >> 16));
  };

  for (int base = beg; base < end; base += 64) {
    const int cnt = min(64, end - base);
    int myidx = (lane < cnt) ? srcList[base + lane] : 0;
    int j = 0;
    for (; j + 15 < cnt; j += 16) {       // 16 edges: 4 instrs, 16 rows in flight
      int s[4];
#pragma unroll
      for (int k = 0; k < 4; ++k) s[k] = __shfl(myidx, j + 4 * k + grp);
      uint4 v[4];
#pragma unroll
      for (int k = 0; k < 4; ++k) v[k] = h16[roff(s[k])];
#pragma unroll
      for (int k = 0; k < 4; ++k) addv(v[k]);
    }
    for (; j < cnt; j += 4) {             // quad tail
      const int idx = j + grp;
      int s0 = __shfl(myidx, min(idx, cnt - 1));
      if (idx < cnt) addv(h16[roff(s0)]);
    }
  }
#pragma unroll
  for (int d = 32; d >= 16; d >>= 1) {
    a0 += __shfl_down(a0, d); a1 += __shfl_down(a1, d);
    a2 += __shfl_down(a2, d); a3 += __shfl_down(a3, d);
    a4 += __shfl_down(a4, d); a5 += __shfl_down(a5, d);
    a6 += __shfl_down(a6, d); a7 += __shfl_down(a7, d);
  }
  if (lane < 16) {
    addv(h16[roff(node)]);                // self term
    uint4 o;
    o.x = ((unsigned)f2bf(a1) << 16) | (unsigned)f2bf(a0);
    o.y = ((unsigned)f2bf(a3) << 16) | (unsigned)f2bf(a2);
    o.z = ((unsigned)f2bf(a5) << 16) | (unsigned)f2bf(a4);
    o.w = ((unsigned)f2bf(a7) << 16) | (unsigned)f2bf(a6);
    ((uint4*)out)[(size_t)node * 16 + (l16 ^ (node & 7))] = o;
  }
}

// Layer-1 gather on x64 (bf16 Nx64 swizzled, 128B rows = 8 uint4).

__global__ void gather_x4(const unsigned short* __restrict__ x64, const int* __restrict__ rowptr,
                          const int* __restrict__ srcList, unsigned short* __restrict__ out, int n) {
  const int tx = threadIdx.x;
  const int node = blockIdx.x * 4 + (tx >> 6);
  if (node >= n) return;
  const int lane = tx & 63;
  const int grp = lane >> 3;              // 8 edge-groups
  const int l8 = lane & 7;                // logical 16B chunk
  const uint4* h16 = (const uint4*)x64;   // row = 8 uint4
  auto roff = [&](int r) { return (size_t)r * 8 + (l8 ^ (r & 7)); };

  const int beg = rowptr[node], end = rowptr[node + 1];
  float a0=0,a1=0,a2=0,a3=0,a4=0,a5=0,a6=0,a7=0;
  auto addv = [&](uint4 vv) {
    a0 += bf2f((unsigned short)vv.x); a1 += bf2f((unsigned short)(vv.x >> 16));
    a2 += bf2f((unsigned short)vv.y); a3 += bf2f((unsigned short)(vv.y >> 16));
    a4 += bf2f((unsigned short)vv.z); a5 += bf2f((unsigned short)(vv.z >> 16));
    a6 += bf2f((unsigned short)vv.w); a7 += bf2f((unsigned short)(vv.w >> 16));
  };

  for (int base = beg; base < end; base += 64) {
    const int cnt = min(64, end - base);
    int myidx = (lane < cnt) ? srcList[base + lane] : 0;
    int j = 0;
    for (; j + 15 < cnt; j += 16) {       // 16 edges: 2 instrs
      int s[2];
#pragma unroll
      for (int k = 0; k < 2; ++k) s[k] = __shfl(myidx, j + 8 * k + grp);
      uint4 v[2];
#pragma unroll
      for (int k = 0; k < 2; ++k) v[k] = h16[roff(s[k])];
#pragma unroll
      for (int k = 0; k < 2; ++k) addv(v[k]);
    }
    for (; j < cnt; j += 8) {             // oct tail
      const int idx = j + grp;
      int s0 = __shfl(myidx, min(idx, cnt - 1));
      if (idx < cnt) addv(h16[roff(s0)]);
    }
  }
#pragma unroll
  for (int d = 32; d >= 8; d >>= 1) {
    a0 += __shfl_down(a0, d); a1 += __shfl_down(a1, d);
    a2 += __shfl_down(a2, d); a3 += __shfl_down(a3, d);
    a4 += __shfl_down(a4, d); a5 += __shfl_down(a5, d);
    a6 += __shfl_down(a6, d); a7 += __shfl_down(a7, d);
  }
  if (lane < 8) {
    addv(h16[roff(node)]);                // self term
    uint4 o;
    o.x = ((unsigned)f2bf(a1) << 16) | (unsigned)f2bf(a0);
    o.y = ((unsigned)f2bf(a3) << 16) | (unsigned)f2bf(a2);
    o.z = ((unsigned)f2bf(a5) << 16) | (unsigned)f2bf(a4);
    o.w = ((unsigned)f2bf(a7) << 16) | (unsigned)f2bf(a6);
    ((uint4*)out)[(size_t)node * 8 + (l8 ^ (node & 7))] = o;
  }
}

// -------- Fused GIN MLP: C = relu(relu(BN(A@W1)) @ W2 + b2), + pool ---------

template <int K1, bool STORE>
__global__ __launch_bounds__(512, 1) void gin_mlp(
    const unsigned short* __restrict__ Ag,   // n x K1 bf16 (swizzled rows)
    const unsigned short* __restrict__ W1t,  // 128 x K1 bf16 (swizzled)
    const unsigned short* __restrict__ W2t,  // 128 x 128 bf16 (swizzled)
    const float* __restrict__ b1, const float* __restrict__ gam,
    const float* __restrict__ bet, const float* __restrict__ mu,
    const float* __restrict__ var, const float* __restrict__ b2,
    unsigned short* __restrict__ Pout,       // n x 128 bf16 (swizzled) or null
    const int* __restrict__ batch,
    float* __restrict__ slab,                // 256 x 8192 per-block partials
    int n) {
  __shared__ __align__(16) unsigned short W1ls[128 * K1];
  __shared__ __align__(16) unsigned short W2ls[128 * 128];
  __shared__ __align__(16) unsigned short Als[64 * K1];
  __shared__ __align__(16) unsigned short Zls[64 * 128];
  __shared__ __align__(16) float poolLs[GG * H];   // 32 KB
  __shared__ float sc1[128], sh1[128], b2l[128];

  const int tx = threadIdx.x;
  const int wv = tx >> 6;                 // wave 0..7
  const int lane = tx & 63;
  const int q = lane >> 4, m = lane & 15;
  const int rowGroup = (wv >> 1) * 16;    // 0,16,32,48
  const int colHalf = (wv & 1) * 64;
  const int ntiles = (n + 63) >> 6;
  const int step = gridDim.x;

  // Stage W once (async; each wave copies distinct 1024B segments).
  constexpr int W1SEG = 128 * K1 / 512;
  for (int s = wv; s < W1SEG; s += 8)
    ld_lds16(W1t + s * 512 + lane * 8, &W1ls[s * 512]);
  for (int s = wv; s < 32; s += 8)
    ld_lds16(W2t + s * 512 + lane * 8, &W2ls[s * 512]);

  // Zero LDS pool.
  {
    f32x4* pl = (f32x4*)poolLs;
    for (int i = tx; i < GG * H / 4; i += 512) pl[i] = (f32x4)(0.f);
  }
  if (tx < 128) {                          // fold bias1 into BN affine
    float s = gam[tx] * rsqrtf(var[tx] + 1e-5f);
    sc1[tx] = s;
    sh1[tx] = bet[tx] + (b1[tx] - mu[tx]) * s;
  } else if (tx < 256) {
    b2l[tx - 128] = b2[tx - 128];
  }

  int tile = blockIdx.x;
  constexpr int ASEG = 64 * K1 / 512;
  if (tile < ntiles) {
    const unsigned short* src = Ag + (size_t)tile * 64 * K1;
    for (int s = wv; s < ASEG; s += 8)
      ld_lds16(src + s * 512 + lane * 8, &Als[s * 512]);
  }
  __syncthreads();                         // drains W + A(tile)

  while (tile < ntiles) {
    // ---- GEMM1: Z = relu(BN(A @ W1 + b1)) ----
    f32x4 acc[4];
#pragma unroll
    for (int t4 = 0; t4 < 4; ++t4) acc[t4] = (f32x4)(0.f);
    const int am = rowGroup + m;
#pragma unroll
    for (int kc = 0; kc < K1 / 32; ++kc) {
      short8 af = *(const short8*)&Als[am * K1 + (((kc * 4 + q) ^ (am & 7)) << 3)];
#pragma unroll
      for (int t4 = 0; t4 < 4; ++t4) {
        const int bn = colHalf + t4 * 16 + m;
        short8 bf = *(const short8*)&W1ls[bn * K1 + (((kc * 4 + q) ^ (bn & 7)) << 3)];
        acc[t4] = __builtin_amdgcn_mfma_f32_16x16x32_bf16(af, bf, acc[t4], 0, 0, 0);
      }
    }
#pragma unroll
    for (int t4 = 0; t4 < 4; ++t4) {       // epilogue -> Zls (bf16, swizzled)
      const int col = colHalf + t4 * 16 + m;
      const float s = sc1[col], hh = sh1[col];
#pragma unroll
      for (int reg = 0; reg < 4; ++reg) {
        const int r = rowGroup + q * 4 + reg;
        float z = fmaf(acc[t4][reg], s, hh);
        z = z > 0.f ? z : 0.f;
        Zls[r * 128 + (((col >> 3) ^ (r & 7)) << 3) + (col & 7)] = f2bf(z);
      }
    }
    __syncthreads();                       // Zls ready; Als free
    const int nt = tile + step;
    if (nt < ntiles) {                     // prefetch next A, overlaps GEMM2
      const unsigned short* src = Ag + (size_t)nt * 64 * K1;
      for (int s = wv; s < ASEG; s += 8)
        ld_lds16(src + s * 512 + lane * 8, &Als[s * 512]);
    }
    // ---- GEMM2: C = relu(Z @ W2 + b2) ----
#pragma unroll
    for (int t4 = 0; t4 < 4; ++t4) acc[t4] = (f32x4)(0.f);
#pragma unroll
    for (int kc = 0; kc < 4; ++kc) {
      short8 af = *(const short8*)&Zls[am * 128 + (((kc * 4 + q) ^ (am & 7)) << 3)];
#pragma unroll
      for (int t4 = 0; t4 < 4; ++t4) {
        const int bn = colHalf + t4 * 16 + m;
        short8 bf = *(const short8*)&W2ls[bn * 128 + (((kc * 4 + q) ^ (bn & 7)) << 3)];
        acc[t4] = __builtin_amdgcn_mfma_f32_16x16x32_bf16(af, bf, acc[t4], 0, 0, 0);
      }
    }
    const int r0 = tile * 64 + rowGroup + q * 4;
    int gb4[4];
#pragma unroll
    for (int reg = 0; reg < 4; ++reg) gb4[reg] = (r0 + reg < n) ? batch[r0 + reg] : -1;
#pragma unroll
    for (int t4 = 0; t4 < 4; ++t4) {
      const int col = colHalf + t4 * 16 + m;
      float v[4];
#pragma unroll
      for (int reg = 0; reg < 4; ++reg) {
        float z = acc[t4][reg] + b2l[col];
        v[reg] = z > 0.f ? z : 0.f;
      }
      if constexpr (STORE) {
#pragma unroll
        for (int reg = 0; reg < 4; ++reg) {
          const int row = r0 + reg;
          if (row < n)
            Pout[(size_t)row * 128 + (((col >> 3) ^ (row & 7)) << 3) + (col & 7)] = f2bf(v[reg]);
        }
      }
      int gcur = -1; float ps = 0.f;       // batch sorted -> run-length flush
#pragma unroll
      for (int reg = 0; reg < 4; ++reg) {
        if (gb4[reg] < 0) break;
        if (gb4[reg] != gcur) {
          if (gcur >= 0) atomicAdd(&poolLs[gcur * H + col], ps);
          gcur = gb4[reg]; ps = v[reg];
        } else {
          ps += v[reg];
        }
      }
      if (gcur >= 0) atomicAdd(&poolLs[gcur * H + col], ps);
    }
    __syncthreads();                       // drains prefetch; Zls free
    tile = nt;
  }

  // Flush per-block pool partial to private slab slice (no contention).
  __syncthreads();
  {
    const f32x4* pl = (const f32x4*)poolLs;
    f32x4* sl = (f32x4*)(slab + (size_t)blockIdx.x * (GG * H));
    for (int i = tx; i < GG * H / 4; i += 512) sl[i] = pl[i];
  }
}

// ------- Head: slab reduce (256 slices x 3 layers) + MLP + sigmoid ----------

__global__ void head2(const float* __restrict__ slab,
                      const float* __restrict__ l1w, const float* __restrict__ l1b,
                      const float* __restrict__ l2w, const float* __restrict__ l2b,
                      const float* __restrict__ l3w, const float* __restrict__ l3b,
                      float* __restrict__ out) {
  const int g = blockIdx.x;
  const int t = threadIdx.x;  // 256 threads
  __shared__ float hin[3 * H];
  __shared__ float t1[50];
  __shared__ float t2[20];
  for (int idx = t; idx < 3 * H; idx += 256) {
    const int l = idx >> 7, f = idx & 127;
    const float* s = slab + (size_t)l * 256 * (GG * H) + (size_t)g * H + f;
    float acc = 0.f;
#pragma unroll 8
    for (int b = 0; b < 256; ++b) acc += s[(size_t)b * (GG * H)];
    hin[idx] = acc;
  }
  __syncthreads();
  if (t < 50) {
    float s = l1b[t];
    for (int k = 0; k < 3 * H; ++k) s = fmaf(hin[k], l1w[k * 50 + t], s);
    t1[t] = s > 0.f ? s : 0.f;
  }
  __syncthreads();
  if (t < 20) {
    float s = l2b[t];
    for (int k = 0; k < 50; ++k) s = fmaf(t1[k], l2w[k * 20 + t], s);
    t2[t] = s > 0.f ? s : 0.f;
  }
  __syncthreads();
  if (t == 0) {
    float s = l3b[0];
    for (int k = 0; k < 20; ++k) s = fmaf(t2[k], l3w[k], s);
    out[g] = 1.f / (1.f + expf(-s));
  }
}

// ---------------- launch ----------------------------------------------------

extern "C" void kernel_launch(void* const* d_in, const int* in_sizes, int n_in,
                              void* d_out, int out_size, void* d_ws, size_t ws_size,
                              hipStream_t stream) {
  const float* x    = (const float*)d_in[0];
  const int* ei     = (const int*)d_in[1];
  const int* batch  = (const int*)d_in[2];
  const int N = in_sizes[2];
  const int E = in_sizes[1] / 2;
  const int* src = ei;
  const int* dst = ei + E;

  const float* w1[3]; const float* b1[3]; const float* gm[3]; const float* be[3];
  const float* mu[3]; const float* vr[3]; const float* w2[3]; const float* b2[3];
  for (int l = 0; l < 3; ++l) {
    int b = 3 + 8 * l;
    w1[l] = (const float*)d_in[b + 0];
    b1[l] = (const float*)d_in[b + 1];
    gm[l] = (const float*)d_in[b + 2];
    be[l] = (const float*)d_in[b + 3];
    mu[l] = (const float*)d_in[b + 4];
    vr[l] = (const float*)d_in[b + 5];
    w2[l] = (const float*)d_in[b + 6];
    b2[l] = (const float*)d_in[b + 7];
  }
  const float* l1w = (const float*)d_in[27];
  const float* l1b = (const float*)d_in[28];
  const float* l2w = (const float*)d_in[29];
  const float* l2b = (const float*)d_in[30];
  const float* l3w = (const float*)d_in[31];
  const float* l3b = (const float*)d_in[32];

  // workspace carve-up
  char* ws = (char*)d_ws;
  size_t off = 0;
  auto take = [&](size_t bytes) {
    size_t p = off;
    off += (bytes + 255) & ~(size_t)255;
    return p;
  };
  unsigned short* A  = (unsigned short*)(ws + take((size_t)N * H * 2));   // agg (bf16, swizzled)
  unsigned short* P  = (unsigned short*)(ws + take((size_t)N * H * 2));   // layer out (bf16, swizzled)
  unsigned short* x64= (unsigned short*)(ws + take((size_t)N * 64 * 2));  // x as bf16 Nx64 swizzled
  float* slab   = (float*)(ws + take((size_t)3 * 256 * GG * H * 4));      // 24 MB partials
  int* rowptr   = (int*)(ws + take((size_t)(N + 1) * 4));
  int* M        = (int*)(ws + take((size_t)256 * 256 * 4));               // bucket counts/offsets
  int* srcList  = (int*)(ws + take((size_t)E * 4));
  unsigned* tmp = (unsigned*)(ws + take((size_t)E * 4));                  // packed (src<<8|dstLocal)
  int* bucketTotal = (int*)(ws + take((size_t)256 * 4));
  unsigned short* Wt[6];
  for (int i = 0; i < 6; ++i) Wt[i] = (unsigned short*)(ws + take((size_t)H * H * 2));
  (void)ws_size; (void)n_in; (void)out_size;

  const int NBLK = 256;
  const int NB = (N + 255) >> 8;          // buckets of 256 nodes (<= 256)
  const int XB = ((size_t)N * 64 + 1023) / 1024;
  const int GB = (N + 3) / 4;             // gather blocks (4 nodes each)

  // prep: csr hist + wconv + xconv, one launch
  PrepArgs pa;
  pa.dst = dst; pa.M = M; pa.E = E; pa.NB = NB; pa.NBLK = NBLK;
  pa.w[0] = w1[0]; pa.K[0] = F_IN; pa.Kp[0] = 64;
  pa.w[1] = w2[0]; pa.K[1] = H;    pa.Kp[1] = H;
  pa.w[2] = w1[1]; pa.K[2] = H;    pa.Kp[2] = H;
  pa.w[3] = w2[1]; pa.K[3] = H;    pa.Kp[3] = H;
  pa.w[4] = w1[2]; pa.K[4] = H;    pa.Kp[4] = H;
  pa.w[5] = w2[2]; pa.K[5] = H;    pa.Kp[5] = H;
  for (int i = 0; i < 6; ++i) pa.o[i] = Wt[i];
  pa.x = x; pa.x64 = x64; pa.N = N;
  prep<<<NBLK + 384 + XB, 256, 0, stream>>>(pa);

  // CSR: per-bucket scan, scatter to tmp, final sort into srcList + rowptr
  scanA<<<NB, 256, 0, stream>>>(M, bucketTotal, NBLK);
  csr_p2<<<NBLK, 256, 0, stream>>>(src, dst, M, bucketTotal, tmp, E, NB);
  csr_p3<<<NB, 256, 0, stream>>>(tmp, bucketTotal, rowptr, srcList, N, E, NB);

  // ---- layer 1 (K padded 33 -> 64) ----
  gather_x4<<<GB, 256, 0, stream>>>(x64, rowptr, srcList, A, N);
  gin_mlp<64, true><<<256, 512, 0, stream>>>(
      A, Wt[0], Wt[1], b1[0], gm[0], be[0], mu[0], vr[0], b2[0],
      P, batch, slab, N);

  // ---- layer 2 ----
  gather_h<<<GB, 256, 0, stream>>>(P, rowptr, srcList, A, N);
  gin_mlp<128, true><<<256, 512, 0, stream>>>(
      A, Wt[2], Wt[3], b1[1], gm[1], be[1], mu[1], vr[1], b2[1],
      P, batch, slab + (size_t)256 * GG * H, N);

  // ---- layer 3 (h3 pooled only) ----
  gather_h<<<GB, 256, 0, stream>>>(P, rowptr, srcList, A, N);
  gin_mlp<128, false><<<256, 512, 0, stream>>>(
      A, Wt[4], Wt[5], b1[2], gm[2], be[2], mu[2], vr[2], b2[2],
      nullptr, batch, slab + (size_t)2 * 256 * GG * H, N);

  // ---- head (slab reduce + MLP + sigmoid) ----
  head2<<<GG, 256, 0, stream>>>(slab, l1w, l1b, l2w, l2b, l3w, l3b, (float*)d_out);
}